// Round 1
// baseline (22.616 us; speedup 1.0000x reference)
//
#include <hip/hip_runtime.h>

#define BLOCK 256

// ---------------------------------------------------------------------------
// Setup kernel: weight-only trig, computed once per launch into d_ws.
// Layout (floats):
//   [0..3]   cos(w_ry/2) layer 0      [4..7]   sin(w_ry/2) layer 0
//   [8..11]  cos(w_ry/2) layer 1      [12..15] sin(w_ry/2) layer 1
//   [16..31] cos(phi_b) layer-0 combined RZ diagonal
//   [32..47] sin(phi_b) layer-0 combined RZ diagonal
// Layer-1 RZ phases are dropped: diagonal phases + CNOT permutations do not
// change |amplitude|^2, and measurement is probability-only.
// ---------------------------------------------------------------------------
__global__ void qc_precompute(const float* __restrict__ w, float* __restrict__ cst) {
    if (threadIdx.x == 0) {
#pragma unroll
        for (int l = 0; l < 2; ++l) {
#pragma unroll
            for (int q = 0; q < 4; ++q) {
                float h = 0.5f * w[l * 8 + q];
                cst[l * 8 + q]     = __cosf(h);
                cst[l * 8 + 4 + q] = __sinf(h);
            }
        }
#pragma unroll
        for (int b = 0; b < 16; ++b) {
            float phi = 0.0f;
#pragma unroll
            for (int q = 0; q < 4; ++q) {
                int bit = (b >> (3 - q)) & 1;
                // RZ(theta): bit0 amp *= e^{-i theta/2}, bit1 amp *= e^{+i theta/2}
                phi += (bit ? 0.5f : -0.5f) * w[4 + q];
            }
            cst[16 + b] = __cosf(phi);
            cst[32 + b] = __sinf(phi);
        }
    }
}

// v_sin_f32 / v_cos_f32 take input in REVOLUTIONS: sin(pi*x/2) = v_sin(x/4).
// x in [0,1) so no range reduction needed.
__device__ __forceinline__ float sin_rev(float r) {
    float o; asm("v_sin_f32 %0, %1" : "=v"(o) : "v"(r)); return o;
}
__device__ __forceinline__ float cos_rev(float r) {
    float o; asm("v_cos_f32 %0, %1" : "=v"(o) : "v"(r)); return o;
}

// CNOT with control mask CM, target mask TM: where control bit set, swap
// target-bit pair. Pure compile-time register permutation.
template <int CM, int TM>
__device__ __forceinline__ void cnot_swap(float (&re)[16], float (&im)[16]) {
#pragma unroll
    for (int idx = 0; idx < 16; ++idx) {
        if ((idx & CM) && !(idx & TM)) {
            const int j = idx | TM;
            float t;
            t = re[idx]; re[idx] = re[j]; re[j] = t;
            t = im[idx]; im[idx] = im[j]; im[j] = t;
        }
    }
}

__global__ __launch_bounds__(BLOCK) void qc_main(const float4* __restrict__ x,
                                                 const float* __restrict__ cst,
                                                 float* __restrict__ out, int B) {
    int i = blockIdx.x * BLOCK + threadIdx.x;
    if (i >= B) return;

    float4 xv = x[i];

    // --- feature encoding: product state, all real --------------------------
    float c0 = cos_rev(xv.x * 0.25f), s0 = sin_rev(xv.x * 0.25f);
    float c1 = cos_rev(xv.y * 0.25f), s1 = sin_rev(xv.y * 0.25f);
    float c2 = cos_rev(xv.z * 0.25f), s2 = sin_rev(xv.z * 0.25f);
    float c3 = cos_rev(xv.w * 0.25f), s3 = sin_rev(xv.w * 0.25f);

    float p01[4], p23[4], a[16];
    p01[0] = c0 * c1; p01[1] = c0 * s1; p01[2] = s0 * c1; p01[3] = s0 * s1;
    p23[0] = c2 * c3; p23[1] = c2 * s3; p23[2] = s2 * c3; p23[3] = s2 * s3;
#pragma unroll
    for (int u = 0; u < 4; ++u)
#pragma unroll
        for (int v = 0; v < 4; ++v)
            a[u * 4 + v] = p01[u] * p23[v];

    // --- layer 0: RY on each qubit (state still real) -----------------------
#pragma unroll
    for (int q = 0; q < 4; ++q) {
        const float cy = cst[q], sy = cst[4 + q];
        const int m = 8 >> q;   // qubit q <-> bit mask (axis 1 = MSB)
#pragma unroll
        for (int idx = 0; idx < 16; ++idx) {
            if (!(idx & m)) {
                float A0 = a[idx], A1 = a[idx | m];
                a[idx]     = cy * A0 - sy * A1;
                a[idx | m] = sy * A0 + cy * A1;
            }
        }
    }

    // --- layer 0: combined RZ diagonal phase (real -> complex) --------------
    float re[16], im[16];
#pragma unroll
    for (int b = 0; b < 16; ++b) {
        re[b] = a[b] * cst[16 + b];
        im[b] = a[b] * cst[32 + b];
    }

    // --- layer 0: CNOT ring (0->1),(1->2),(2->3),(3->0) ---------------------
    cnot_swap<8, 4>(re, im);
    cnot_swap<4, 2>(re, im);
    cnot_swap<2, 1>(re, im);
    cnot_swap<1, 8>(re, im);

    // --- layer 1: RY on each qubit (complex state) --------------------------
#pragma unroll
    for (int q = 0; q < 4; ++q) {
        const float cy = cst[8 + q], sy = cst[12 + q];
        const int m = 8 >> q;
#pragma unroll
        for (int idx = 0; idx < 16; ++idx) {
            if (!(idx & m)) {
                float r0 = re[idx], r1 = re[idx | m];
                float i0 = im[idx], i1 = im[idx | m];
                re[idx]     = cy * r0 - sy * r1;
                re[idx | m] = sy * r0 + cy * r1;
                im[idx]     = cy * i0 - sy * i1;
                im[idx | m] = sy * i0 + cy * i1;
            }
        }
    }

    // --- layer 1: RZ skipped (diagonal phase, |amp|^2-invariant) ------------
    // --- layer 1: CNOT ring -------------------------------------------------
    cnot_swap<8, 4>(re, im);
    cnot_swap<4, 2>(re, im);
    cnot_swap<2, 1>(re, im);
    cnot_swap<1, 8>(re, im);

    // --- <Z_0> = P(bit8=0) - P(bit8=1) --------------------------------------
    float pos = 0.0f, neg = 0.0f;
#pragma unroll
    for (int idx = 0; idx < 16; ++idx) {
        float n = re[idx] * re[idx] + im[idx] * im[idx];
        if (idx < 8) pos += n; else neg += n;
    }
    out[i] = pos - neg;
}

extern "C" void kernel_launch(void* const* d_in, const int* in_sizes, int n_in,
                              void* d_out, int out_size, void* d_ws, size_t ws_size,
                              hipStream_t stream) {
    const float* x = (const float*)d_in[0];
    const float* w = (const float*)d_in[1];
    float* out = (float*)d_out;
    float* cst = (float*)d_ws;   // 48 floats used
    int B = in_sizes[0] / 4;

    qc_precompute<<<1, 64, 0, stream>>>(w, cst);
    qc_main<<<(B + BLOCK - 1) / BLOCK, BLOCK, 0, stream>>>((const float4*)x, cst, out, B);
}

// Round 2
// 13.329 us; speedup vs baseline: 1.6968x; 1.6968x over previous
//
#include <hip/hip_runtime.h>

#define BLOCK 256
#define INV_2PI 0.15915494309189535f

// ---------------------------------------------------------------------------
// Heisenberg-picture collapse: <Z0> after the full circuit equals a sum of 8
// Pauli-string expectations on the PRODUCT state existing before the first
// CNOT ring. Per qubit q: phi_q = pi*x_q + w[q] (encoding RY + layer-0 RY
// fuse), beta_q = w[4+q] (layer-0 RZ). Bloch vector:
//   z_q = cos phi_q,  x_q = sin phi_q cos beta_q,  y_q = sin phi_q sin beta_q
// Layer-1 RY angles th_q = w[8+q] enter only via C_q=cos th_q, S_q=sin th_q
// for q=1,2,3 (q0's layer-1 RY commutes with the pushed-through observable;
// all RZ weights of layer 1 and w[8], w[12..15] drop out).
//
//   E =  C1C2C3 * z0 z1 z3
//      - C1C2S3 * x0 x1 z2 x3
//      + C1S2C3 * y2 y3
//      - C1S2S3 * y0 y1 x2
//      - S1C2C3 * x1 x2 z3
//      - S1C2S3 * y0 z1 y2 x3
//      - S1S2C3 * z0 y1 z2 y3
//      - S1S2S3 * x0
//
// cst layout: [0..3] w[q]/(2pi) rev offsets, [4..7] cos(beta), [8..11]
// sin(beta), [12..19] the 8 signed coefficients above.
// ---------------------------------------------------------------------------
__global__ void qc_precompute(const float* __restrict__ w, float* __restrict__ cst) {
    if (threadIdx.x == 0) {
#pragma unroll
        for (int q = 0; q < 4; ++q) {
            cst[q]     = w[q] * INV_2PI;
            cst[4 + q] = __cosf(w[4 + q]);
            cst[8 + q] = __sinf(w[4 + q]);
        }
        float C1 = __cosf(w[9]),  S1 = __sinf(w[9]);
        float C2 = __cosf(w[10]), S2 = __sinf(w[10]);
        float C3 = __cosf(w[11]), S3 = __sinf(w[11]);
        cst[12] =  C1 * C2 * C3;   // z0 z1 z3
        cst[13] = -C1 * C2 * S3;   // x0 x1 z2 x3
        cst[14] =  C1 * S2 * C3;   // y2 y3
        cst[15] = -C1 * S2 * S3;   // y0 y1 x2
        cst[16] = -S1 * C2 * C3;   // x1 x2 z3
        cst[17] = -S1 * C2 * S3;   // y0 z1 y2 x3
        cst[18] = -S1 * S2 * C3;   // z0 y1 z2 y3
        cst[19] = -S1 * S2 * S3;   // x0
    }
}

// v_sin/v_cos take REVOLUTIONS; args here are in [-0.01, 0.51] — in range.
__device__ __forceinline__ float sin_rev(float r) {
    float o; asm("v_sin_f32 %0, %1" : "=v"(o) : "v"(r)); return o;
}
__device__ __forceinline__ float cos_rev(float r) {
    float o; asm("v_cos_f32 %0, %1" : "=v"(o) : "v"(r)); return o;
}

__global__ __launch_bounds__(BLOCK) void qc_main(const float4* __restrict__ x,
                                                 const float* __restrict__ cst,
                                                 float* __restrict__ out, int B) {
    int i = blockIdx.x * BLOCK + threadIdx.x;
    if (i >= B) return;

    float4 xv = x[i];

    // uniform constants -> scalar loads
    const float ra0 = cst[0],  ra1 = cst[1],  ra2 = cst[2],  ra3 = cst[3];
    const float cb0 = cst[4],  cb1 = cst[5],  cb2 = cst[6],  cb3 = cst[7];
    const float sb0 = cst[8],  sb1 = cst[9],  sb2 = cst[10], sb3 = cst[11];
    const float K0 = cst[12], K1 = cst[13], K2 = cst[14], K3 = cst[15];
    const float K4 = cst[16], K5 = cst[17], K6 = cst[18], K7 = cst[19];

    // Bloch vectors: phi_rev = x/2 + w/(2pi)
    float r0 = fmaf(xv.x, 0.5f, ra0);
    float r1 = fmaf(xv.y, 0.5f, ra1);
    float r2 = fmaf(xv.z, 0.5f, ra2);
    float r3 = fmaf(xv.w, 0.5f, ra3);

    float zb0 = cos_rev(r0), sn0 = sin_rev(r0);
    float zb1 = cos_rev(r1), sn1 = sin_rev(r1);
    float zb2 = cos_rev(r2), sn2 = sin_rev(r2);
    float zb3 = cos_rev(r3), sn3 = sin_rev(r3);

    float xb0 = sn0 * cb0, yb0 = sn0 * sb0;
    float xb1 = sn1 * cb1, yb1 = sn1 * sb1;
    float xb2 = sn2 * cb2, yb2 = sn2 * sb2;
    float xb3 = sn3 * cb3, yb3 = sn3 * sb3;

    float e = K7 * xb0;
    e = fmaf((K0 * zb0) * zb1,  zb3,        e);
    e = fmaf((K1 * xb0) * xb1,  zb2 * xb3,  e);
    e = fmaf( K2 * yb2,         yb3,        e);
    e = fmaf((K3 * yb0) * yb1,  xb2,        e);
    e = fmaf((K4 * xb1) * xb2,  zb3,        e);
    e = fmaf((K5 * yb0) * zb1,  yb2 * xb3,  e);
    e = fmaf((K6 * zb0) * yb1,  zb2 * yb3,  e);

    out[i] = e;
}

extern "C" void kernel_launch(void* const* d_in, const int* in_sizes, int n_in,
                              void* d_out, int out_size, void* d_ws, size_t ws_size,
                              hipStream_t stream) {
    const float* x = (const float*)d_in[0];
    const float* w = (const float*)d_in[1];
    float* out = (float*)d_out;
    float* cst = (float*)d_ws;   // 20 floats used
    int B = in_sizes[0] / 4;

    qc_precompute<<<1, 64, 0, stream>>>(w, cst);
    qc_main<<<(B + BLOCK - 1) / BLOCK, BLOCK, 0, stream>>>((const float4*)x, cst, out, B);
}

// Round 3
// 10.059 us; speedup vs baseline: 2.2484x; 1.3250x over previous
//
#include <hip/hip_runtime.h>

#define BLOCK 256
#define INV_2PI 0.15915494309189535f

// ---------------------------------------------------------------------------
// Heisenberg-picture collapse (derivation verified round 1->2): <Z0> after
// the full 2-layer circuit equals a sum of 8 Pauli-string expectations on the
// product state preceding the first CNOT ring. Per qubit q:
//   phi_q = pi*x_q + w[q]   (encoding RY + layer-0 RY fuse)
//   beta_q = w[4+q]         (layer-0 RZ)
//   z_q = cos phi_q, x_q = sin phi_q cos beta_q, y_q = sin phi_q sin beta_q
// Layer-1 RY angles enter only via C_q/S_q = cos/sin(w[8+q]) for q=1,2,3;
// w[8], w[12..15] (layer-1 RZ) drop out.
//
//   E =  C1C2C3 * z0 z1 z3      - C1C2S3 * x0 x1 z2 x3
//      + C1S2C3 * y2 y3         - C1S2S3 * y0 y1 x2
//      - S1C2C3 * x1 x2 z3      - S1C2S3 * y0 z1 y2 x3
//      - S1S2C3 * z0 y1 z2 y3   - S1S2S3 * x0
//
// Single fused kernel: weight-derived constants are wave-uniform and cheap
// (14 trig + ~20 mults, hidden under the memory-bound budget) — recomputed
// per thread to avoid a second dispatch + serialization.
// ---------------------------------------------------------------------------

// v_sin/v_cos take REVOLUTIONS; args here are in (-0.01, 0.51) — in range.
__device__ __forceinline__ float sin_rev(float r) {
    float o; asm("v_sin_f32 %0, %1" : "=v"(o) : "v"(r)); return o;
}
__device__ __forceinline__ float cos_rev(float r) {
    float o; asm("v_cos_f32 %0, %1" : "=v"(o) : "v"(r)); return o;
}

struct QCConsts {
    float ra0, ra1, ra2, ra3;          // w[q]/(2pi) revolution offsets
    float cb0, cb1, cb2, cb3;          // cos(beta_q)
    float sb0, sb1, sb2, sb3;          // sin(beta_q)
    float K0, K1, K2, K3, K4, K5, K6, K7;
};

__device__ __forceinline__ float qc_eval(const float4 xv, const QCConsts& k) {
    float r0 = fmaf(xv.x, 0.5f, k.ra0);
    float r1 = fmaf(xv.y, 0.5f, k.ra1);
    float r2 = fmaf(xv.z, 0.5f, k.ra2);
    float r3 = fmaf(xv.w, 0.5f, k.ra3);

    float zb0 = cos_rev(r0), sn0 = sin_rev(r0);
    float zb1 = cos_rev(r1), sn1 = sin_rev(r1);
    float zb2 = cos_rev(r2), sn2 = sin_rev(r2);
    float zb3 = cos_rev(r3), sn3 = sin_rev(r3);

    float xb0 = sn0 * k.cb0, yb0 = sn0 * k.sb0;
    float xb1 = sn1 * k.cb1, yb1 = sn1 * k.sb1;
    float xb2 = sn2 * k.cb2, yb2 = sn2 * k.sb2;
    float xb3 = sn3 * k.cb3, yb3 = sn3 * k.sb3;

    float e = k.K7 * xb0;
    e = fmaf((k.K0 * zb0) * zb1,  zb3,        e);
    e = fmaf((k.K1 * xb0) * xb1,  zb2 * xb3,  e);
    e = fmaf( k.K2 * yb2,         yb3,        e);
    e = fmaf((k.K3 * yb0) * yb1,  xb2,        e);
    e = fmaf((k.K4 * xb1) * xb2,  zb3,        e);
    e = fmaf((k.K5 * yb0) * zb1,  yb2 * xb3,  e);
    e = fmaf((k.K6 * zb0) * yb1,  zb2 * yb3,  e);
    return e;
}

__global__ __launch_bounds__(BLOCK) void qc_fused(const float4* __restrict__ x,
                                                  const float* __restrict__ w,
                                                  float* __restrict__ out, int B) {
    const int half = (B + 1) >> 1;
    const int i = blockIdx.x * BLOCK + threadIdx.x;
    if (i >= half) return;

    // --- weight-derived constants (uniform; scalar loads of w) --------------
    QCConsts k;
    k.ra0 = w[0] * INV_2PI;  k.ra1 = w[1] * INV_2PI;
    k.ra2 = w[2] * INV_2PI;  k.ra3 = w[3] * INV_2PI;
    k.cb0 = __cosf(w[4]);  k.sb0 = __sinf(w[4]);
    k.cb1 = __cosf(w[5]);  k.sb1 = __sinf(w[5]);
    k.cb2 = __cosf(w[6]);  k.sb2 = __sinf(w[6]);
    k.cb3 = __cosf(w[7]);  k.sb3 = __sinf(w[7]);
    const float C1 = __cosf(w[9]),  S1 = __sinf(w[9]);
    const float C2 = __cosf(w[10]), S2 = __sinf(w[10]);
    const float C3 = __cosf(w[11]), S3 = __sinf(w[11]);
    k.K0 =  C1 * C2 * C3;   // z0 z1 z3
    k.K1 = -C1 * C2 * S3;   // x0 x1 z2 x3
    k.K2 =  C1 * S2 * C3;   // y2 y3
    k.K3 = -C1 * S2 * S3;   // y0 y1 x2
    k.K4 = -S1 * C2 * C3;   // x1 x2 z3
    k.K5 = -S1 * C2 * S3;   // y0 z1 y2 x3
    k.K6 = -S1 * S2 * C3;   // z0 y1 z2 y3
    k.K7 = -S1 * S2 * S3;   // x0

    // --- two elements per thread, split-halves (both streams coalesced) ----
    out[i] = qc_eval(x[i], k);
    const int j = i + half;
    if (j < B) out[j] = qc_eval(x[j], k);
}

extern "C" void kernel_launch(void* const* d_in, const int* in_sizes, int n_in,
                              void* d_out, int out_size, void* d_ws, size_t ws_size,
                              hipStream_t stream) {
    const float* x = (const float*)d_in[0];
    const float* w = (const float*)d_in[1];
    float* out = (float*)d_out;
    int B = in_sizes[0] / 4;
    int half = (B + 1) >> 1;

    qc_fused<<<(half + BLOCK - 1) / BLOCK, BLOCK, 0, stream>>>(
        (const float4*)x, w, out, B);
}